// Round 16
// baseline (69.924 us; speedup 1.0000x reference)
//
#include <hip/hip_runtime.h>
#include <hip/hip_fp16.h>

// OptimalTransportDepthLoss: B=65536 rows of D=256.
// loss = mean_b [ mean_i (P-Q)^2 + EMD2(P/sumP, Q/sumQ) ]
//
// EMD2 via rank formula over the stable merge of the two CDFs (validated
// rounds 3..15):
//   cp-emission at merged pos k:  coef = 2k - 4i - 1  (0 if i==255)
//   cq-emission at merged pos k:  coef = 4i - 2k - 1  (0 if j==255)
// u = 4i - 2k - 1:  coef = ea ? -(u+2) : u, u += ea ? +2 : -2. 255-elem
// zeroing fires only at merged pos 510/511 (row maxima): single correction
// e -= |cp255 - cq255| at the last lane of each half.
//
// Round 16: r15 half-wave split + r13 split-chain. r15 cut LDS ops/row to
// ~27 (pipe has slack) but ran corank(9)+merge(16) serially = 25 dependent
// levels/pair -> latency-bound (VALUBusy ~45%). Now corank(p+1) runs
// step-interleaved with merge(p): depth 25 -> 16 levels/pair. loC carried
// in a register; corank reads the freshly staged buffer via the in-order
// per-wave DS pipe (r13-validated). All else identical to r15: lanes 0-31
// own row 2p / lanes 32-63 row 2p+1 (8 elems/lane), 5-step DPP half scans,
// f16 staging (u16-bit compares), double-buffered wave-private LDS, no
// lgkmcnt asm, register prefetch of pair p+2, f64 accumulation, (256,6).

#define NW    4      // waves per block
#define DSZ   256    // histogram length
#define LROW  264    // u16: 256 vals + sentinel@256 + readahead pad; 8B-aligned

template <int CTRL, int RMASK, bool BC>
__device__ __forceinline__ float dpp_add(float x) {
    int t = __builtin_amdgcn_update_dpp(0, __float_as_int(x), CTRL, RMASK, 0xf, BC);
    return x + __int_as_float(t);
}

// 32-lane inclusive scan within each wave half
__device__ __forceinline__ float half_scan(float x) {
    x = dpp_add<0x111, 0xf, true >(x);   // row_shr:1
    x = dpp_add<0x112, 0xf, true >(x);   // row_shr:2
    x = dpp_add<0x114, 0xf, true >(x);   // row_shr:4
    x = dpp_add<0x118, 0xf, true >(x);   // row_shr:8
    x = dpp_add<0x142, 0xa, false>(x);   // row_bcast:15 -> rows 1,3
    return x;
}

__device__ __forceinline__ float rdlane31(float x) {
    return __int_as_float(__builtin_amdgcn_readlane(__float_as_int(x), 31));
}
__device__ __forceinline__ float rdlane63(float x) {
    return __int_as_float(__builtin_amdgcn_readlane(__float_as_int(x), 63));
}

__device__ __forceinline__ unsigned int f2h(float x) {
    return (unsigned int)__half_as_ushort(__float2half(x));  // RTN
}
__device__ __forceinline__ float h2f(unsigned int x) {
    return __half2float(__ushort_as_half((unsigned short)x));
}

// front-end: each lane handles 8 elems of its half's row; stages f16 CDF
// (one b128 per array); returns the lane's MSE partial.
__device__ __forceinline__ float fe_stage(
    const float4 pA, const float4 pB, const float4 qA, const float4 qB,
    unsigned short* cp, unsigned short* cq, int l32, bool hiHalf)
{
    float d0 = pA.x - qA.x, d1 = pA.y - qA.y, d2 = pA.z - qA.z, d3 = pA.w - qA.w;
    float d4 = pB.x - qB.x, d5 = pB.y - qB.y, d6 = pB.z - qB.z, d7 = pB.w - qB.w;
    float msel = d0*d0 + d1*d1 + d2*d2 + d3*d3 + d4*d4 + d5*d5 + d6*d6 + d7*d7;

    float pl = (pA.x + pA.y + pA.z + pA.w) + (pB.x + pB.y + pB.z + pB.w);
    float ql = (qA.x + qA.y + qA.z + qA.w) + (qB.x + qB.y + qB.z + qB.w);
    float ps = half_scan(pl);
    float qs = half_scan(ql);

    float ptot = hiHalf ? rdlane63(ps) : rdlane31(ps);
    float qtot = hiHalf ? rdlane63(qs) : rdlane31(qs);
    float rp = __builtin_amdgcn_rcpf(ptot);
    float rq = __builtin_amdgcn_rcpf(qtot);
    float pe = ps - pl, qe = qs - ql;

    float p0 = pe + pA.x, p1 = p0 + pA.y, p2 = p1 + pA.z, p3 = p2 + pA.w;
    float p4 = p3 + pB.x, p5 = p4 + pB.y, p6 = p5 + pB.z;
    float q0 = qe + qA.x, q1 = q0 + qA.y, q2 = q1 + qA.z, q3 = q2 + qA.w;
    float q4 = q3 + qB.x, q5 = q4 + qB.y, q6 = q5 + qB.z;

    uint4 wp, wq;
    wp.x = f2h(p0 * rp) | (f2h(p1 * rp) << 16);
    wp.y = f2h(p2 * rp) | (f2h(p3 * rp) << 16);
    wp.z = f2h(p4 * rp) | (f2h(p5 * rp) << 16);
    wp.w = f2h(p6 * rp) | (f2h(ps * rp) << 16);
    wq.x = f2h(q0 * rq) | (f2h(q1 * rq) << 16);
    wq.y = f2h(q2 * rq) | (f2h(q3 * rq) << 16);
    wq.z = f2h(q4 * rq) | (f2h(q5 * rq) << 16);
    wq.w = f2h(q6 * rq) | (f2h(qs * rq) << 16);

    *reinterpret_cast<uint4*>(&cp[l32 * 8]) = wp;   // one ds_write_b128
    *reinterpret_cast<uint4*>(&cq[l32 * 8]) = wq;
    return msel;
}

// corank(pair p+1) step-interleaved with merge(pair p).
// Returns EMD partial of pair p's row-half; writes corank of p+1 to loN.
__device__ __forceinline__ float corank_merge(
    const unsigned short* cpN, const unsigned short* cqN,  // next pair (search)
    const unsigned short* cpC, const unsigned short* cqC,  // cur pair (merge)
    int k0, int loC, bool isLast, int& loN)
{
    // corank state (pair p+1): smallest i in [lo,hi] with cq[k0-1-i] <= cp[i]
    int lo = k0 > DSZ ? k0 - DSZ : 0;
    int hi = k0 < DSZ ? k0 : DSZ;

    // merge init (pair p)
    const unsigned short* pA_ = cpC + loC;
    const unsigned short* pB_ = cqC + (k0 - loC);
    float u  = (float)(4 * loC - 2 * k0 - 1);
    unsigned int a  = pA_[0];
    unsigned int b2 = pB_[0];
    unsigned int an = pA_[1];
    unsigned int bn = pB_[1];
    float e_ = 0.0f;
#pragma unroll
    for (int s = 0; s < 16; ++s) {
        if (s < 9) {   // corank step s (independent LDS chain)
            int mid = (lo + hi) >> 1;
            int jm  = k0 - 1 - mid;
            int jr  = jm < 0 ? 0 : jm;
            unsigned int qq = cqN[jr];
            unsigned int cc = cpN[mid];
            bool pred = (jm < 0) || (qq <= cc);
            hi = pred ? mid : hi;
            lo = pred ? lo  : mid + 1;
        }
        {   // merge step s
            bool  ea   = a < b2;
            float val  = h2f(ea ? a : b2);
            float u2   = u + 2.0f;
            float coef = ea ? -u2 : u;
            e_ = fmaf(val, coef, e_);
            u  = ea ? u2 : (u - 2.0f);
            pA_ += ea ? 1 : 0;
            pB_ += ea ? 0 : 1;
            a  = ea ? an : a;
            b2 = ea ? b2 : bn;
            an = pA_[1];
            bn = pB_[1];
        }
    }
    loN = lo;
    // last-lane correction: merged pos 510/511 hold the row maxima with
    // true coef 0; uncorrected sum is +/-(cp255-cq255).
    e_ -= isLast ? fabsf(h2f(cpC[DSZ - 1]) - h2f(cqC[DSZ - 1])) : 0.0f;
    return e_;
}

__global__ __launch_bounds__(256, 6) void otdl_main(
    const float* __restrict__ P, const float* __restrict__ Q,
    double* __restrict__ partial, int B, int bpw)
{
    __shared__ unsigned short s_cp[NW][2][2][LROW];   // [wave][buf][rowhalf][...]
    __shared__ unsigned short s_cq[NW][2][2][LROW];
    __shared__ double s_bsum[NW];

    const int tid  = threadIdx.x;
    const int wv   = tid >> 6;
    const int lane = tid & 63;
    const int l32  = lane & 31;
    const bool hiHalf = (lane >= 32);
    const int rh   = hiHalf ? 1 : 0;
    const int wgl  = blockIdx.x * NW + wv;   // global wave id

    // f16 sentinel 2.0 (0x4000) > all CDF values; wave-private, ordered by
    // the in-order DS pipe before any later read.
    if (lane == 0) {
#pragma unroll
        for (int bf = 0; bf < 2; ++bf)
#pragma unroll
            for (int r2 = 0; r2 < 2; ++r2) {
                s_cp[wv][bf][r2][DSZ] = 0x4000;
                s_cq[wv][bf][r2][DSZ] = 0x4000;
            }
    }

    double acc = 0.0;
    const int  k0      = l32 * 16;           // this lane's merge diagonal
    const int  npair   = (bpw + 1) >> 1;
    const long rowbase = (long)wgl * bpw;
    const bool isLast  = (l32 == 31);

    // load pair 0 (each lane: its half's row, 8 elems)
    float4 pA, pB, qA, qB;
    {
        long b = rowbase + rh;
        long c = (b < B) ? b : (B - 1);
        const float4* Pr = reinterpret_cast<const float4*>(P + c * DSZ + l32 * 8);
        const float4* Qr = reinterpret_cast<const float4*>(Q + c * DSZ + l32 * 8);
        pA = Pr[0]; pB = Pr[1];
        qA = Qr[0]; qB = Qr[1];
    }

    // prologue: FE+stage pair 0 -> buf0, standalone corank(pair 0), load pair 1
    float mselC = fe_stage(pA, pB, qA, qB, s_cp[wv][0][rh], s_cq[wv][0][rh],
                           l32, hiHalf);
    if (npair > 1) {
        long b = rowbase + 2 + rh;
        long c = (b < B) ? b : (B - 1);
        const float4* Pr = reinterpret_cast<const float4*>(P + c * DSZ + l32 * 8);
        const float4* Qr = reinterpret_cast<const float4*>(Q + c * DSZ + l32 * 8);
        pA = Pr[0]; pB = Pr[1];
        qA = Qr[0]; qB = Qr[1];
    }
    int loC;
    {
        const unsigned short* cp = s_cp[wv][0][rh];
        const unsigned short* cq = s_cq[wv][0][rh];
        int lo = k0 > DSZ ? k0 - DSZ : 0;
        int hi = k0 < DSZ ? k0 : DSZ;
#pragma unroll
        for (int s = 0; s < 9; ++s) {
            int mid = (lo + hi) >> 1;
            int jm  = k0 - 1 - mid;
            int jr  = jm < 0 ? 0 : jm;
            unsigned int qq = cq[jr];
            unsigned int cc = cp[mid];
            bool pred = (jm < 0) || (qq <= cc);
            hi = pred ? mid : hi;
            lo = pred ? lo  : mid + 1;
        }
        loC = lo;
    }

#pragma unroll 2
    for (int p = 0; p < npair; ++p) {
        const int cur = p & 1;
        unsigned short* cpN = s_cp[wv][cur ^ 1][rh];
        unsigned short* cqN = s_cq[wv][cur ^ 1][rh];
        const unsigned short* cpC = s_cp[wv][cur][rh];
        const unsigned short* cqC = s_cq[wv][cur][rh];

        // ---- FE+stage pair p+1 into the other buffer ----
        float mselN = 0.0f;
        if (p + 1 < npair) {
            mselN = fe_stage(pA, pB, qA, qB, cpN, cqN, l32, hiHalf);
        }
        // ---- issue global loads for pair p+2 ----
        if (p + 2 < npair) {
            long b = rowbase + 2 * (p + 2) + rh;
            long c = (b < B) ? b : (B - 1);
            const float4* Pr = reinterpret_cast<const float4*>(P + c * DSZ + l32 * 8);
            const float4* Qr = reinterpret_cast<const float4*>(Q + c * DSZ + l32 * 8);
            pA = Pr[0]; pB = Pr[1];
            qA = Qr[0]; qB = Qr[1];
        }

        // ---- corank(p+1) || merge(p), step-interleaved ----
        // (corank reads cpN even when p+1>=npair: stale data, result unused)
        int loN;
        float e_ = corank_merge(cpN, cqN, cpC, cqC, k0, loC, isLast, loN);

        if (rowbase + 2 * p + rh < B)
            acc += (double)(e_ + mselC * (1.0f / 256.0f));
        mselC = mselN;
        loC   = loN;
    }

    // ---- wave reduce (f64) sums both halves' rows, then block reduce ----
#pragma unroll
    for (int off = 32; off; off >>= 1) {
        double o = __shfl_xor(acc, off, 64);
        acc += o;
    }
    if (lane == 0) s_bsum[wv] = acc;
    __syncthreads();
    if (tid == 0) {
        partial[blockIdx.x] = s_bsum[0] + s_bsum[1] + s_bsum[2] + s_bsum[3];
    }
}

__global__ __launch_bounds__(256) void otdl_reduce(
    const double* __restrict__ partial, int n, float* __restrict__ out, double invB)
{
    __shared__ double sdata[256];
    double a = 0.0;
    for (int i = threadIdx.x; i < n; i += 256) a += partial[i];
    sdata[threadIdx.x] = a;
    __syncthreads();
    for (int s2 = 128; s2 > 0; s2 >>= 1) {
        if (threadIdx.x < s2) sdata[threadIdx.x] += sdata[threadIdx.x + s2];
        __syncthreads();
    }
    if (threadIdx.x == 0) out[0] = (float)(sdata[0] * invB);
}

extern "C" void kernel_launch(void* const* d_in, const int* in_sizes, int n_in,
                              void* d_out, int out_size, void* d_ws, size_t ws_size,
                              hipStream_t stream)
{
    const float* P = (const float*)d_in[0];
    const float* Q = (const float*)d_in[1];
    float* out = (float*)d_out;
    double* partial = (double*)d_ws;

    int B = in_sizes[0] / DSZ;          // 65536
    const int blocks = 2048;
    const int totalWaves = blocks * NW; // 8192
    int bpw = (B + totalWaves - 1) / totalWaves;  // 8

    otdl_main<<<blocks, 256, 0, stream>>>(P, Q, partial, B, bpw);
    otdl_reduce<<<1, 256, 0, stream>>>(partial, blocks, out, 1.0 / (double)B);
}

// Round 17
// 38.453 us; speedup vs baseline: 1.8184x; 1.8184x over previous
//
#include <hip/hip_runtime.h>
#include <hip/hip_fp16.h>

// OptimalTransportDepthLoss: B=65536 rows of D=256.
// loss = mean_b [ mean_i (P-Q)^2 + EMD2(P/sumP, Q/sumQ) ]
//
// EMD2 via rank formula over the stable merge of the two CDFs (validated
// rounds 3..15):
//   cp-emission at merged pos k:  coef = 2k - 4i - 1  (0 if i==255)
//   cq-emission at merged pos k:  coef = 4i - 2k - 1  (0 if j==255)
// u = 4i - 2k - 1:  coef = ea ? -(u+2) : u, u += ea ? +2 : -2. 255-elem
// zeroing fires only at merged pos 510/511 (row maxima): single correction
// e -= |cp255 - cq255| at the last lane of each half.
//
// Round 17: r16 (half-wave split + split-chain corank(p+1)||merge(p))
// WITHOUT the spill: r16's 84MB WRITE_SIZE came from corank state living
// across the merge + unroll-2 body doubling under the (256,6) 85-VGPR cap.
// Fixes: (a) no unroll-2 — `cur` only selects LDS pointers (runtime LDS
// addressing is fine; rule-20 is about register arrays); (b) (256,4) =
// 128-VGPR cap (r10-validated, no spill at VGPR 52; the 16-wave/CU cap is
// not binding at measured ~43% occupancy). All math identical to r15/r16:
// lanes 0-31 own row 2p / lanes 32-63 row 2p+1 (8 elems/lane), 5-step DPP
// half scans, f16 staging (u16-bit compares), double-buffered wave-private
// LDS, no lgkmcnt asm (per-wave DS in-order), prefetch of pair p+2, f64
// accumulation.

#define NW    4      // waves per block
#define DSZ   256    // histogram length
#define LROW  264    // u16: 256 vals + sentinel@256 + readahead pad; 8B-aligned

template <int CTRL, int RMASK, bool BC>
__device__ __forceinline__ float dpp_add(float x) {
    int t = __builtin_amdgcn_update_dpp(0, __float_as_int(x), CTRL, RMASK, 0xf, BC);
    return x + __int_as_float(t);
}

// 32-lane inclusive scan within each wave half
__device__ __forceinline__ float half_scan(float x) {
    x = dpp_add<0x111, 0xf, true >(x);   // row_shr:1
    x = dpp_add<0x112, 0xf, true >(x);   // row_shr:2
    x = dpp_add<0x114, 0xf, true >(x);   // row_shr:4
    x = dpp_add<0x118, 0xf, true >(x);   // row_shr:8
    x = dpp_add<0x142, 0xa, false>(x);   // row_bcast:15 -> rows 1,3
    return x;
}

__device__ __forceinline__ float rdlane31(float x) {
    return __int_as_float(__builtin_amdgcn_readlane(__float_as_int(x), 31));
}
__device__ __forceinline__ float rdlane63(float x) {
    return __int_as_float(__builtin_amdgcn_readlane(__float_as_int(x), 63));
}

__device__ __forceinline__ unsigned int f2h(float x) {
    return (unsigned int)__half_as_ushort(__float2half(x));  // RTN
}
__device__ __forceinline__ float h2f(unsigned int x) {
    return __half2float(__ushort_as_half((unsigned short)x));
}

// front-end: each lane handles 8 elems of its half's row; stages f16 CDF
// (one b128 per array); returns the lane's MSE partial.
__device__ __forceinline__ float fe_stage(
    const float4 pA, const float4 pB, const float4 qA, const float4 qB,
    unsigned short* cp, unsigned short* cq, int l32, bool hiHalf)
{
    float d0 = pA.x - qA.x, d1 = pA.y - qA.y, d2 = pA.z - qA.z, d3 = pA.w - qA.w;
    float d4 = pB.x - qB.x, d5 = pB.y - qB.y, d6 = pB.z - qB.z, d7 = pB.w - qB.w;
    float msel = d0*d0 + d1*d1 + d2*d2 + d3*d3 + d4*d4 + d5*d5 + d6*d6 + d7*d7;

    float pl = (pA.x + pA.y + pA.z + pA.w) + (pB.x + pB.y + pB.z + pB.w);
    float ql = (qA.x + qA.y + qA.z + qA.w) + (qB.x + qB.y + qB.z + qB.w);
    float ps = half_scan(pl);
    float qs = half_scan(ql);

    float ptot = hiHalf ? rdlane63(ps) : rdlane31(ps);
    float qtot = hiHalf ? rdlane63(qs) : rdlane31(qs);
    float rp = __builtin_amdgcn_rcpf(ptot);
    float rq = __builtin_amdgcn_rcpf(qtot);
    float pe = ps - pl, qe = qs - ql;

    float p0 = pe + pA.x, p1 = p0 + pA.y, p2 = p1 + pA.z, p3 = p2 + pA.w;
    float p4 = p3 + pB.x, p5 = p4 + pB.y, p6 = p5 + pB.z;
    float q0 = qe + qA.x, q1 = q0 + qA.y, q2 = q1 + qA.z, q3 = q2 + qA.w;
    float q4 = q3 + qB.x, q5 = q4 + qB.y, q6 = q5 + qB.z;

    uint4 wp, wq;
    wp.x = f2h(p0 * rp) | (f2h(p1 * rp) << 16);
    wp.y = f2h(p2 * rp) | (f2h(p3 * rp) << 16);
    wp.z = f2h(p4 * rp) | (f2h(p5 * rp) << 16);
    wp.w = f2h(p6 * rp) | (f2h(ps * rp) << 16);
    wq.x = f2h(q0 * rq) | (f2h(q1 * rq) << 16);
    wq.y = f2h(q2 * rq) | (f2h(q3 * rq) << 16);
    wq.z = f2h(q4 * rq) | (f2h(q5 * rq) << 16);
    wq.w = f2h(q6 * rq) | (f2h(qs * rq) << 16);

    *reinterpret_cast<uint4*>(&cp[l32 * 8]) = wp;   // one ds_write_b128
    *reinterpret_cast<uint4*>(&cq[l32 * 8]) = wq;
    return msel;
}

// corank(pair p+1) step-interleaved with merge(pair p).
// Returns EMD partial of pair p's row-half; writes corank of p+1 to loN.
__device__ __forceinline__ float corank_merge(
    const unsigned short* cpN, const unsigned short* cqN,  // next pair (search)
    const unsigned short* cpC, const unsigned short* cqC,  // cur pair (merge)
    int k0, int loC, bool isLast, int& loN)
{
    // corank state (pair p+1): smallest i in [lo,hi] with cq[k0-1-i] <= cp[i]
    int lo = k0 > DSZ ? k0 - DSZ : 0;
    int hi = k0 < DSZ ? k0 : DSZ;

    // merge init (pair p)
    const unsigned short* pA_ = cpC + loC;
    const unsigned short* pB_ = cqC + (k0 - loC);
    float u  = (float)(4 * loC - 2 * k0 - 1);
    unsigned int a  = pA_[0];
    unsigned int b2 = pB_[0];
    unsigned int an = pA_[1];
    unsigned int bn = pB_[1];
    float e_ = 0.0f;
#pragma unroll
    for (int s = 0; s < 16; ++s) {
        if (s < 9) {   // corank step s (independent LDS chain)
            int mid = (lo + hi) >> 1;
            int jm  = k0 - 1 - mid;
            int jr  = jm < 0 ? 0 : jm;
            unsigned int qq = cqN[jr];
            unsigned int cc = cpN[mid];
            bool pred = (jm < 0) || (qq <= cc);
            hi = pred ? mid : hi;
            lo = pred ? lo  : mid + 1;
        }
        {   // merge step s
            bool  ea   = a < b2;
            float val  = h2f(ea ? a : b2);
            float u2   = u + 2.0f;
            float coef = ea ? -u2 : u;
            e_ = fmaf(val, coef, e_);
            u  = ea ? u2 : (u - 2.0f);
            pA_ += ea ? 1 : 0;
            pB_ += ea ? 0 : 1;
            a  = ea ? an : a;
            b2 = ea ? b2 : bn;
            an = pA_[1];
            bn = pB_[1];
        }
    }
    loN = lo;
    // last-lane correction: merged pos 510/511 hold the row maxima with
    // true coef 0; uncorrected sum is +/-(cp255-cq255).
    e_ -= isLast ? fabsf(h2f(cpC[DSZ - 1]) - h2f(cqC[DSZ - 1])) : 0.0f;
    return e_;
}

__global__ __launch_bounds__(256, 4) void otdl_main(
    const float* __restrict__ P, const float* __restrict__ Q,
    double* __restrict__ partial, int B, int bpw)
{
    __shared__ unsigned short s_cp[NW][2][2][LROW];   // [wave][buf][rowhalf][...]
    __shared__ unsigned short s_cq[NW][2][2][LROW];
    __shared__ double s_bsum[NW];

    const int tid  = threadIdx.x;
    const int wv   = tid >> 6;
    const int lane = tid & 63;
    const int l32  = lane & 31;
    const bool hiHalf = (lane >= 32);
    const int rh   = hiHalf ? 1 : 0;
    const int wgl  = blockIdx.x * NW + wv;   // global wave id

    // f16 sentinel 2.0 (0x4000) > all CDF values; wave-private, ordered by
    // the in-order DS pipe before any later read.
    if (lane == 0) {
#pragma unroll
        for (int bf = 0; bf < 2; ++bf)
#pragma unroll
            for (int r2 = 0; r2 < 2; ++r2) {
                s_cp[wv][bf][r2][DSZ] = 0x4000;
                s_cq[wv][bf][r2][DSZ] = 0x4000;
            }
    }

    double acc = 0.0;
    const int  k0      = l32 * 16;           // this lane's merge diagonal
    const int  npair   = (bpw + 1) >> 1;
    const long rowbase = (long)wgl * bpw;
    const bool isLast  = (l32 == 31);

    // load pair 0 (each lane: its half's row, 8 elems)
    float4 pA, pB, qA, qB;
    {
        long b = rowbase + rh;
        long c = (b < B) ? b : (B - 1);
        const float4* Pr = reinterpret_cast<const float4*>(P + c * DSZ + l32 * 8);
        const float4* Qr = reinterpret_cast<const float4*>(Q + c * DSZ + l32 * 8);
        pA = Pr[0]; pB = Pr[1];
        qA = Qr[0]; qB = Qr[1];
    }

    // prologue: FE+stage pair 0 -> buf0, standalone corank(pair 0), load pair 1
    float mselC = fe_stage(pA, pB, qA, qB, s_cp[wv][0][rh], s_cq[wv][0][rh],
                           l32, hiHalf);
    if (npair > 1) {
        long b = rowbase + 2 + rh;
        long c = (b < B) ? b : (B - 1);
        const float4* Pr = reinterpret_cast<const float4*>(P + c * DSZ + l32 * 8);
        const float4* Qr = reinterpret_cast<const float4*>(Q + c * DSZ + l32 * 8);
        pA = Pr[0]; pB = Pr[1];
        qA = Qr[0]; qB = Qr[1];
    }
    int loC;
    {
        const unsigned short* cp = s_cp[wv][0][rh];
        const unsigned short* cq = s_cq[wv][0][rh];
        int lo = k0 > DSZ ? k0 - DSZ : 0;
        int hi = k0 < DSZ ? k0 : DSZ;
#pragma unroll
        for (int s = 0; s < 9; ++s) {
            int mid = (lo + hi) >> 1;
            int jm  = k0 - 1 - mid;
            int jr  = jm < 0 ? 0 : jm;
            unsigned int qq = cq[jr];
            unsigned int cc = cp[mid];
            bool pred = (jm < 0) || (qq <= cc);
            hi = pred ? mid : hi;
            lo = pred ? lo  : mid + 1;
        }
        loC = lo;
    }

    for (int p = 0; p < npair; ++p) {
        const int cur = p & 1;
        unsigned short* cpN = s_cp[wv][cur ^ 1][rh];
        unsigned short* cqN = s_cq[wv][cur ^ 1][rh];
        const unsigned short* cpC = s_cp[wv][cur][rh];
        const unsigned short* cqC = s_cq[wv][cur][rh];

        // ---- FE+stage pair p+1 into the other buffer ----
        float mselN = 0.0f;
        if (p + 1 < npair) {
            mselN = fe_stage(pA, pB, qA, qB, cpN, cqN, l32, hiHalf);
        }
        // ---- issue global loads for pair p+2 ----
        if (p + 2 < npair) {
            long b = rowbase + 2 * (p + 2) + rh;
            long c = (b < B) ? b : (B - 1);
            const float4* Pr = reinterpret_cast<const float4*>(P + c * DSZ + l32 * 8);
            const float4* Qr = reinterpret_cast<const float4*>(Q + c * DSZ + l32 * 8);
            pA = Pr[0]; pB = Pr[1];
            qA = Qr[0]; qB = Qr[1];
        }

        // ---- corank(p+1) || merge(p), step-interleaved ----
        // (corank reads cpN even when p+1>=npair: stale data, result unused)
        int loN;
        float e_ = corank_merge(cpN, cqN, cpC, cqC, k0, loC, isLast, loN);

        if (rowbase + 2 * p + rh < B)
            acc += (double)(e_ + mselC * (1.0f / 256.0f));
        mselC = mselN;
        loC   = loN;
    }

    // ---- wave reduce (f64) sums both halves' rows, then block reduce ----
#pragma unroll
    for (int off = 32; off; off >>= 1) {
        double o = __shfl_xor(acc, off, 64);
        acc += o;
    }
    if (lane == 0) s_bsum[wv] = acc;
    __syncthreads();
    if (tid == 0) {
        partial[blockIdx.x] = s_bsum[0] + s_bsum[1] + s_bsum[2] + s_bsum[3];
    }
}

__global__ __launch_bounds__(256) void otdl_reduce(
    const double* __restrict__ partial, int n, float* __restrict__ out, double invB)
{
    __shared__ double sdata[256];
    double a = 0.0;
    for (int i = threadIdx.x; i < n; i += 256) a += partial[i];
    sdata[threadIdx.x] = a;
    __syncthreads();
    for (int s2 = 128; s2 > 0; s2 >>= 1) {
        if (threadIdx.x < s2) sdata[threadIdx.x] += sdata[threadIdx.x + s2];
        __syncthreads();
    }
    if (threadIdx.x == 0) out[0] = (float)(sdata[0] * invB);
}

extern "C" void kernel_launch(void* const* d_in, const int* in_sizes, int n_in,
                              void* d_out, int out_size, void* d_ws, size_t ws_size,
                              hipStream_t stream)
{
    const float* P = (const float*)d_in[0];
    const float* Q = (const float*)d_in[1];
    float* out = (float*)d_out;
    double* partial = (double*)d_ws;

    int B = in_sizes[0] / DSZ;          // 65536
    const int blocks = 2048;
    const int totalWaves = blocks * NW; // 8192
    int bpw = (B + totalWaves - 1) / totalWaves;  // 8

    otdl_main<<<blocks, 256, 0, stream>>>(P, Q, partial, B, bpw);
    otdl_reduce<<<1, 256, 0, stream>>>(partial, blocks, out, 1.0 / (double)B);
}